// Round 3
// baseline (600.507 us; speedup 1.0000x reference)
//
#include <hip/hip_runtime.h>
#include <hip/hip_cooperative_groups.h>
#include <stdint.h>
#include <limits.h>

namespace cg = cooperative_groups;

// Problem constants (fixed by the reference file)
#define BB 4
#define NI 64
#define CC 16
#define KK 4
#define HH 480
#define WW 480
#define PLANE (HH * WW)      // 230400 pixels per (b,c) plane
#define NG (PLANE / 4)       // 57600 groups-of-4-pixels per plane
#define TPB 256
#define BIGV (1 << 30)
#define NPLANE (BB * CC)     // 64

// ---- fused (cooperative) geometry ----
// 64 planes x 25 chunks = 1600 blocks, 256 thr, 9 groups/thread (25*256*9 = 57600).
// Round-2 post-mortem: VGPR=24 + 3.75 blocks/CU -> 1.2 KB in flight/CU -> 1.1 TB/s
// (latency-bound). Fix: 1600 blocks (~25 waves/CU) + depth-1 prefetch (10 loads
// in flight/wave). __launch_bounds__(256,7): VGPR cap ~72, capacity 7*256=1792>=1600.
#define FBPP 25
#define FGPT 9

// ---- fallback (3-kernel) geometry, proven at 388 us ----
#define BPP 45               // 45 * 256 * 5 = 57600 groups
#define GPT 5

typedef float  v4f __attribute__((ext_vector_type(4)));
typedef int    v4i __attribute__((ext_vector_type(4)));

// Workspace layout (fallback path): sel8 bytes then ints.
#define SEL8_BYTES ((size_t)NPLANE * PLANE)
#define PART_STRIDE 8
#define MAP_OFF (NPLANE * BPP * PART_STRIDE)
// Fused path uses d_ws base directly for its partial array:
//   fpart[plane][chunk(25)][8] ints = 12800 ints (50 KB). Never concurrent with fallback.

__device__ __forceinline__ int wred_min(int v) {
    for (int o = 32; o; o >>= 1) v = min(v, __shfl_down(v, o, 64));
    return v;
}
__device__ __forceinline__ int wred_max(int v) {
    for (int o = 32; o; o >>= 1) v = max(v, __shfl_down(v, o, 64));
    return v;
}
__device__ __forceinline__ int wred_or(int v) {
    for (int o = 32; o; o >>= 1) v |= __shfl_down(v, o, 64);
    return v;
}

// ============================================================================
// FUSED cooperative kernel: stats + mapping + remap in one dispatch.
//  - packed (sel,glob) bytes held in LDS across the grid sync
//  - depth-1 software prefetch in phase 1: iteration i+1's 5 dwordx4 loads are
//    issued before iteration i's values are consumed -> compiler emits counted
//    vmcnt waits, 10 loads/wave in flight (round 2 had 5 -> 1.1 TB/s)
//  - mapping computed redundantly per-block so only ONE grid sync is needed
// ============================================================================
__global__ __launch_bounds__(TPB, 7) void fused_kernel(
    const float* __restrict__ update, const int* __restrict__ initmap,
    const int* __restrict__ inst_ids, int* __restrict__ out,
    int* __restrict__ wsi) {

    __shared__ unsigned int s_sel[TPB * FGPT];   // 9216 B: packed p = sel*50+glob
    __shared__ int red[4][6];
    __shared__ int s_red[CC][6];
    __shared__ int s_ids[CC * KK];
    __shared__ int s_map[KK];

    int plane = blockIdx.x / FBPP;      // 0..63  (b*16 + ci)
    int chunk = blockIdx.x % FBPP;
    int b = plane >> 4;

    int idbase = plane * KK;
    int id0 = inst_ids[idbase + 0], id1 = inst_ids[idbase + 1];
    int id2 = inst_ids[idbase + 2], id3 = inst_ids[idbase + 3];

    const v4f* u0 = (const v4f*)(update + ((size_t)b * NI + id0) * PLANE);
    const v4f* u1 = (const v4f*)(update + ((size_t)b * NI + id1) * PLANE);
    const v4f* u2 = (const v4f*)(update + ((size_t)b * NI + id2) * PLANE);
    const v4f* u3 = (const v4f*)(update + ((size_t)b * NI + id3) * PLANE);
    const v4i* gl = (const v4i*)(initmap + (size_t)plane * PLANE);

    int lmin0 = INT_MAX, lmin1 = INT_MAX, lmin2 = INT_MAX, lmin3 = INT_MAX;
    int pres = 0, gmax = 0;

    int base = chunk * (TPB * FGPT);

    // ---- phase 1 with depth-1 prefetch ----
    int g0 = base + threadIdx.x;
    v4f pa = __builtin_nontemporal_load(&u0[g0]);
    v4f pb = __builtin_nontemporal_load(&u1[g0]);
    v4f pc = __builtin_nontemporal_load(&u2[g0]);
    v4f pd = __builtin_nontemporal_load(&u3[g0]);
    v4i pg = __builtin_nontemporal_load(&gl[g0]);

#pragma unroll
    for (int it = 0; it < FGPT; it++) {
        v4f a = pa, b2 = pb, c = pc, d = pd; v4i gv = pg;
        if (it + 1 < FGPT) {           // issue next-iteration loads NOW
            int gn = base + (it + 1) * TPB + threadIdx.x;
            pa = __builtin_nontemporal_load(&u0[gn]);
            pb = __builtin_nontemporal_load(&u1[gn]);
            pc = __builtin_nontemporal_load(&u2[gn]);
            pd = __builtin_nontemporal_load(&u3[gn]);
            pg = __builtin_nontemporal_load(&gl[gn]);
        }

        unsigned int packed = 0;
#pragma unroll
        for (int e = 0; e < 4; e++) {
            float best = 1e-5f; int s = 0;
            if (a[e]  > best) { best = a[e];  s = 1; }
            if (b2[e] > best) { best = b2[e]; s = 2; }
            if (c[e]  > best) { best = c[e];  s = 3; }
            if (d[e]  > best) { s = 4; }
            int gve = gv[e];
            packed |= (unsigned int)(s * 50 + gve) << (8 * e);
            gmax = max(gmax, gve);
            if (s) {
                int kk = s - 1; pres |= 1 << kk;
                int v = gve ? gve : BIGV;
                if (kk == 0) lmin0 = min(lmin0, v);
                else if (kk == 1) lmin1 = min(lmin1, v);
                else if (kk == 2) lmin2 = min(lmin2, v);
                else lmin3 = min(lmin3, v);
            }
        }
        s_sel[it * TPB + threadIdx.x] = packed;   // LDS, conflict-free stride
    }

    // block reduce -> one partial record per block
    lmin0 = wred_min(lmin0); lmin1 = wred_min(lmin1);
    lmin2 = wred_min(lmin2); lmin3 = wred_min(lmin3);
    pres = wred_or(pres); gmax = wred_max(gmax);

    int wv = threadIdx.x >> 6, lane = threadIdx.x & 63;
    if (lane == 0) {
        red[wv][0] = lmin0; red[wv][1] = lmin1; red[wv][2] = lmin2;
        red[wv][3] = lmin3; red[wv][4] = pres;  red[wv][5] = gmax;
    }
    __syncthreads();
    if (threadIdx.x == 0) {
        int m0 = red[0][0], m1 = red[0][1], m2 = red[0][2], m3 = red[0][3];
        int pr = red[0][4], gm = red[0][5];
        for (int w2 = 1; w2 < 4; w2++) {
            m0 = min(m0, red[w2][0]); m1 = min(m1, red[w2][1]);
            m2 = min(m2, red[w2][2]); m3 = min(m3, red[w2][3]);
            pr |= red[w2][4]; gm = max(gm, red[w2][5]);
        }
        int* pp = wsi + ((size_t)plane * FBPP + chunk) * PART_STRIDE;
        pp[0] = m0; pp[1] = m1; pp[2] = m2; pp[3] = m3; pp[4] = pr; pp[5] = gm;
    }

    // one grid-wide sync: all partial records visible everywhere after this
    cg::this_grid().sync();

    // ---- phase 2: every block rebuilds the mapping for its own b ----
    if (threadIdx.x < CC * KK) s_ids[threadIdx.x] = inst_ids[b * (CC * KK) + threadIdx.x];
    if (threadIdx.x < CC * 6) {
        int p16 = threadIdx.x / 6, slot = threadIdx.x % 6;
        const int* rp = wsi + ((size_t)(b * CC + p16) * FBPP) * PART_STRIDE + slot;
        int v = (slot < 4) ? INT_MAX : 0;
        for (int ch = 0; ch < FBPP; ch++) {
            int x = rp[ch * PART_STRIDE];
            if (slot < 4)      v = min(v, x);
            else if (slot == 4) v |= x;
            else               v = max(v, x);
        }
        s_red[p16][slot] = v;
    }
    __syncthreads();

    if (threadIdx.x == 0) {
        int max_id = 0;
        for (int ci = 0; ci < CC; ci++) max_id = max(max_id, s_red[ci][5]);
        int my_ci = plane & (CC - 1);
        for (int ci = 0; ci <= my_ci; ci++) {
            int id[KK], ov[KK], prb[KK];
            int prbits = s_red[ci][4];
            for (int t = 0; t < KK; t++) {
                id[t] = s_ids[ci * KK + t];
                ov[t] = s_red[ci][t];
                prb[t] = (prbits >> t) & 1;
            }
            int ord[KK] = {0, 1, 2, 3};
            for (int i = 1; i < KK; i++) {      // insertion sort by id
                int key = ord[i], j = i - 1;
                while (j >= 0 && id[ord[j]] > id[key]) { ord[j + 1] = ord[j]; j--; }
                ord[j + 1] = key;
            }
            int map_slot[KK];
            int prev_id = -1, cur_map = 0, cnt_new = 0;
            for (int j = 0; j < KK; j++) {
                int s = ord[j], l = id[s];
                if (l != prev_id) {
                    int cov = INT_MAX, cpr = 0;
                    for (int t = 0; t < KK; t++)
                        if (id[t] == l) { cov = min(cov, ov[t]); cpr |= prb[t]; }
                    if (l == 0) cur_map = 0;
                    else {
                        bool has = cov < BIGV;
                        bool isnew = cpr && !has;
                        if (isnew) { cnt_new++; cur_map = max_id + cnt_new; }
                        else cur_map = has ? cov : 0;
                    }
                    prev_id = l;
                }
                map_slot[s] = cur_map;
            }
            if (ci == my_ci) {
                s_map[0] = map_slot[0]; s_map[1] = map_slot[1];
                s_map[2] = map_slot[2]; s_map[3] = map_slot[3];
            }
            max_id += cnt_new;
        }
    }
    __syncthreads();

    int m0 = s_map[0], m1 = s_map[1], m2 = s_map[2], m3 = s_map[3];

    // ---- phase 3: remap from LDS, stream output ----
    v4i* op = (v4i*)(out + (size_t)plane * PLANE);
#pragma unroll
    for (int it = 0; it < FGPT; it++) {
        int g = base + it * TPB + threadIdx.x;
        unsigned int u = s_sel[it * TPB + threadIdx.x];
        v4i ov;
#pragma unroll
        for (int e = 0; e < 4; e++) {
            unsigned int p = (u >> (8 * e)) & 0xFFu;
            int s = (int)((p * 41u) >> 11);     // exact p/50 for p in [0,249]
            int gvv = (int)p - s * 50;
            int mv = (s == 1) ? m0 : (s == 2) ? m1 : (s == 3) ? m2 : m3;
            ov[e] = s ? max(gvv, mv) : gvv;
        }
        __builtin_nontemporal_store(ov, &op[g]);
    }
}

// ============================================================================
// Fallback path: the proven 3-kernel pipeline (388 us), used only if the
// cooperative launch is rejected by the runtime.
// ============================================================================
__global__ __launch_bounds__(TPB) void stats_kernel(
    const float* __restrict__ update, const int* __restrict__ initmap,
    const int* __restrict__ inst_ids, unsigned int* __restrict__ sel8,
    int* __restrict__ wsi) {
    int plane = blockIdx.x / BPP;
    int chunk = blockIdx.x % BPP;
    int b = plane >> 4;

    int idbase = plane * KK;
    int id0 = inst_ids[idbase + 0], id1 = inst_ids[idbase + 1];
    int id2 = inst_ids[idbase + 2], id3 = inst_ids[idbase + 3];

    const v4f* u0 = (const v4f*)(update + ((size_t)b * NI + id0) * PLANE);
    const v4f* u1 = (const v4f*)(update + ((size_t)b * NI + id1) * PLANE);
    const v4f* u2 = (const v4f*)(update + ((size_t)b * NI + id2) * PLANE);
    const v4f* u3 = (const v4f*)(update + ((size_t)b * NI + id3) * PLANE);
    const v4i* gl = (const v4i*)(initmap + (size_t)plane * PLANE);
    unsigned int* sp = sel8 + (size_t)plane * NG;

    int lmin0 = INT_MAX, lmin1 = INT_MAX, lmin2 = INT_MAX, lmin3 = INT_MAX;
    int pres = 0, gmax = 0;

    int base = chunk * (TPB * GPT);
#pragma unroll
    for (int it = 0; it < GPT; it++) {
        int g = base + it * TPB + threadIdx.x;
        v4f a  = __builtin_nontemporal_load(&u0[g]);
        v4f b2 = __builtin_nontemporal_load(&u1[g]);
        v4f c  = __builtin_nontemporal_load(&u2[g]);
        v4f d  = __builtin_nontemporal_load(&u3[g]);
        v4i gv = __builtin_nontemporal_load(&gl[g]);

        unsigned int packed = 0;
#pragma unroll
        for (int e = 0; e < 4; e++) {
            float best = 1e-5f; int s = 0;
            if (a[e]  > best) { best = a[e];  s = 1; }
            if (b2[e] > best) { best = b2[e]; s = 2; }
            if (c[e]  > best) { best = c[e];  s = 3; }
            if (d[e]  > best) { s = 4; }
            int gve = gv[e];
            packed |= (unsigned int)(s * 50 + gve) << (8 * e);
            gmax = max(gmax, gve);
            if (s) {
                int kk = s - 1; pres |= 1 << kk;
                int v = gve ? gve : BIGV;
                if (kk == 0) lmin0 = min(lmin0, v);
                else if (kk == 1) lmin1 = min(lmin1, v);
                else if (kk == 2) lmin2 = min(lmin2, v);
                else lmin3 = min(lmin3, v);
            }
        }
        sp[g] = packed;
    }

    lmin0 = wred_min(lmin0); lmin1 = wred_min(lmin1);
    lmin2 = wred_min(lmin2); lmin3 = wred_min(lmin3);
    pres = wred_or(pres); gmax = wred_max(gmax);

    __shared__ int red[4][6];
    int wv = threadIdx.x >> 6, lane = threadIdx.x & 63;
    if (lane == 0) {
        red[wv][0] = lmin0; red[wv][1] = lmin1; red[wv][2] = lmin2;
        red[wv][3] = lmin3; red[wv][4] = pres;  red[wv][5] = gmax;
    }
    __syncthreads();
    if (threadIdx.x == 0) {
        int m0 = red[0][0], m1 = red[0][1], m2 = red[0][2], m3 = red[0][3];
        int pr = red[0][4], gm = red[0][5];
        for (int w2 = 1; w2 < 4; w2++) {
            m0 = min(m0, red[w2][0]); m1 = min(m1, red[w2][1]);
            m2 = min(m2, red[w2][2]); m3 = min(m3, red[w2][3]);
            pr |= red[w2][4]; gm = max(gm, red[w2][5]);
        }
        int* pp = wsi + ((size_t)plane * BPP + chunk) * PART_STRIDE;
        pp[0] = m0; pp[1] = m1; pp[2] = m2; pp[3] = m3; pp[4] = pr; pp[5] = gm;
    }
}

__global__ void mapping_kernel(const int* __restrict__ inst_ids, int* wsi) {
    __shared__ int s_ov[NPLANE][4];
    __shared__ int s_pr[NPLANE];
    __shared__ int s_gm[NPLANE];

    int plane = threadIdx.x;
    int m0 = INT_MAX, m1 = INT_MAX, m2 = INT_MAX, m3 = INT_MAX, pr = 0, gm = 0;
    for (int ch = 0; ch < BPP; ch++) {
        const int* pp = wsi + ((size_t)plane * BPP + ch) * PART_STRIDE;
        m0 = min(m0, pp[0]); m1 = min(m1, pp[1]);
        m2 = min(m2, pp[2]); m3 = min(m3, pp[3]);
        pr |= pp[4]; gm = max(gm, pp[5]);
    }
    s_ov[plane][0] = m0; s_ov[plane][1] = m1;
    s_ov[plane][2] = m2; s_ov[plane][3] = m3;
    s_pr[plane] = pr; s_gm[plane] = gm;
    __syncthreads();

    if (threadIdx.x < BB) {
        int b = threadIdx.x;
        int max_id = 0;
        for (int ci = 0; ci < CC; ci++) max_id = max(max_id, s_gm[b * CC + ci]);
        for (int ci = 0; ci < CC; ci++) {
            int pl = b * CC + ci;
            int base = pl * KK;
            int id[KK], ov[KK], prb[KK];
            int prbits = s_pr[pl];
            for (int t = 0; t < KK; t++) {
                id[t] = inst_ids[base + t];
                ov[t] = s_ov[pl][t];
                prb[t] = (prbits >> t) & 1;
            }
            int ord[KK] = {0, 1, 2, 3};
            for (int i = 1; i < KK; i++) {
                int key = ord[i], j = i - 1;
                while (j >= 0 && id[ord[j]] > id[key]) { ord[j + 1] = ord[j]; j--; }
                ord[j + 1] = key;
            }
            int map_slot[KK];
            int prev_id = -1, cur_map = 0, cnt_new = 0;
            for (int j = 0; j < KK; j++) {
                int s = ord[j], l = id[s];
                if (l != prev_id) {
                    int cov = INT_MAX, cpr = 0;
                    for (int t = 0; t < KK; t++)
                        if (id[t] == l) { cov = min(cov, ov[t]); cpr |= prb[t]; }
                    if (l == 0) cur_map = 0;
                    else {
                        bool has = cov < BIGV;
                        bool isnew = cpr && !has;
                        if (isnew) { cnt_new++; cur_map = max_id + cnt_new; }
                        else cur_map = has ? cov : 0;
                    }
                    prev_id = l;
                }
                map_slot[s] = cur_map;
            }
            for (int t = 0; t < KK; t++) wsi[MAP_OFF + base + t] = map_slot[t];
            max_id += cnt_new;
        }
    }
}

__global__ __launch_bounds__(TPB) void remap_kernel(
    const unsigned int* __restrict__ sel8, const int* __restrict__ wsi,
    int* __restrict__ out) {
    int plane = blockIdx.x / BPP;
    int chunk = blockIdx.x % BPP;

    int m0 = wsi[MAP_OFF + plane * 4 + 0];
    int m1 = wsi[MAP_OFF + plane * 4 + 1];
    int m2 = wsi[MAP_OFF + plane * 4 + 2];
    int m3 = wsi[MAP_OFF + plane * 4 + 3];

    const unsigned int* sp = sel8 + (size_t)plane * NG;
    v4i* op = (v4i*)(out + (size_t)plane * PLANE);

    int base = chunk * (TPB * GPT);
#pragma unroll
    for (int it = 0; it < GPT; it++) {
        int g = base + it * TPB + threadIdx.x;
        unsigned int u = sp[g];
        v4i ov;
#pragma unroll
        for (int e = 0; e < 4; e++) {
            unsigned int p = (u >> (8 * e)) & 0xFFu;
            int s = (int)((p * 41u) >> 11);
            int gvv = (int)p - s * 50;
            int mv = (s == 1) ? m0 : (s == 2) ? m1 : (s == 3) ? m2 : m3;
            ov[e] = s ? max(gvv, mv) : gvv;
        }
        __builtin_nontemporal_store(ov, &op[g]);
    }
}

extern "C" void kernel_launch(void* const* d_in, const int* in_sizes, int n_in,
                              void* d_out, int out_size, void* d_ws, size_t ws_size,
                              hipStream_t stream) {
    const float* update = (const float*)d_in[0];
    const int* initmap = (const int*)d_in[1];
    const int* inst_ids = (const int*)d_in[2];
    int* out = (int*)d_out;

    // Fused path: partials live at the base of the workspace (12800 ints).
    int* wsi_fused = (int*)d_ws;
    void* args[] = { (void*)&update, (void*)&initmap, (void*)&inst_ids,
                     (void*)&out, (void*)&wsi_fused };
    hipError_t e = hipLaunchCooperativeKernel(
        (const void*)fused_kernel, dim3(NPLANE * FBPP), dim3(TPB),
        args, 0, stream);

    if (e != hipSuccess) {
        (void)hipGetLastError();   // clear error, fall back to 3-kernel path
        unsigned int* sel8 = (unsigned int*)d_ws;
        int* wsi = (int*)((uint8_t*)d_ws + SEL8_BYTES);
        stats_kernel<<<NPLANE * BPP, TPB, 0, stream>>>(update, initmap, inst_ids, sel8, wsi);
        mapping_kernel<<<1, NPLANE, 0, stream>>>(inst_ids, wsi);
        remap_kernel<<<NPLANE * BPP, TPB, 0, stream>>>(sel8, wsi, out);
    }
}

// Round 4
// 524.863 us; speedup vs baseline: 1.1441x; 1.1441x over previous
//
#include <hip/hip_runtime.h>
#include <stdint.h>
#include <limits.h>

// Problem constants (fixed by the reference file)
#define BB 4
#define NI 64
#define CC 16
#define KK 4
#define HH 480
#define WW 480
#define PLANE (HH * WW)      // 230400 pixels per (b,c) plane
#define NG (PLANE / 4)       // 57600 groups-of-4-pixels per plane
#define BPP 45               // blocks per plane (45 * 256 * 5 = 57600 groups)
#define GPT 5
#define TPB 256
#define BIGV (1 << 30)
#define NPLANE (BB * CC)     // 64
#define NBLK (NPLANE * BPP)  // 2880 blocks

// Native vector types
typedef float  v4f __attribute__((ext_vector_type(4)));
typedef int    v4i __attribute__((ext_vector_type(4)));

// Workspace layout:
//   [0, SEL8_BYTES)  : uint8 per pixel, packed p = sel*50 + glob (one uint per 4 px)
//   ints after that:
//     partials[plane][chunk][8] : 64*45*8 ints (slots 0-3 overlap_min, 4 present, 5 gmax)
//     mapping[plane][4]         : 256 ints at MAP_OFF
//     done-counter              : 1 int at CNT_IDX (zeroed via hipMemsetAsync each launch)
#define SEL8_BYTES ((size_t)NPLANE * PLANE)
#define PART_STRIDE 8
#define MAP_OFF (NPLANE * BPP * PART_STRIDE)
#define CNT_IDX (MAP_OFF + 256)

__device__ __forceinline__ int wred_min(int v) {
    for (int o = 32; o; o >>= 1) v = min(v, __shfl_down(v, o, 64));
    return v;
}
__device__ __forceinline__ int wred_max(int v) {
    for (int o = 32; o; o >>= 1) v = max(v, __shfl_down(v, o, 64));
    return v;
}
__device__ __forceinline__ int wred_or(int v) {
    for (int o = 32; o; o >>= 1) v |= __shfl_down(v, o, 64);
    return v;
}

// ============================================================================
// Kernel A: per-pixel (sel,glob) byte pack + per-block partial stats +
// last-block-done mapping construction (replaces the old 1-block kernel B,
// removing one kernel launch + its latency from the critical path).
// ============================================================================
__global__ __launch_bounds__(TPB) void stats_map_kernel(
    const float* __restrict__ update, const int* __restrict__ initmap,
    const int* __restrict__ inst_ids, unsigned int* __restrict__ sel8,
    int* __restrict__ wsi) {
    int plane = blockIdx.x / BPP;       // 0..63  (b*16 + ci)
    int chunk = blockIdx.x % BPP;
    int b = plane >> 4;

    int idbase = plane * KK;
    int id0 = inst_ids[idbase + 0], id1 = inst_ids[idbase + 1];
    int id2 = inst_ids[idbase + 2], id3 = inst_ids[idbase + 3];

    const v4f* u0 = (const v4f*)(update + ((size_t)b * NI + id0) * PLANE);
    const v4f* u1 = (const v4f*)(update + ((size_t)b * NI + id1) * PLANE);
    const v4f* u2 = (const v4f*)(update + ((size_t)b * NI + id2) * PLANE);
    const v4f* u3 = (const v4f*)(update + ((size_t)b * NI + id3) * PLANE);
    const v4i* gl = (const v4i*)(initmap + (size_t)plane * PLANE);
    unsigned int* sp = sel8 + (size_t)plane * NG;

    int lmin0 = INT_MAX, lmin1 = INT_MAX, lmin2 = INT_MAX, lmin3 = INT_MAX;
    int pres = 0, gmax = 0;

    int base = chunk * (TPB * GPT);
#pragma unroll
    for (int it = 0; it < GPT; it++) {
        int g = base + it * TPB + threadIdx.x;
        // streaming inputs: nontemporal; sel8 store stays cached for pass C
        v4f a  = __builtin_nontemporal_load(&u0[g]);
        v4f b2 = __builtin_nontemporal_load(&u1[g]);
        v4f c  = __builtin_nontemporal_load(&u2[g]);
        v4f d  = __builtin_nontemporal_load(&u3[g]);
        v4i gv = __builtin_nontemporal_load(&gl[g]);

        unsigned int packed = 0;
#pragma unroll
        for (int e = 0; e < 4; e++) {
            float best = 1e-5f; int s = 0;
            if (a[e]  > best) { best = a[e];  s = 1; }
            if (b2[e] > best) { best = b2[e]; s = 2; }
            if (c[e]  > best) { best = c[e];  s = 3; }
            if (d[e]  > best) { s = 4; }
            int gve = gv[e];
            packed |= (unsigned int)(s * 50 + gve) << (8 * e);
            gmax = max(gmax, gve);
            if (s) {
                int kk = s - 1; pres |= 1 << kk;
                int v = gve ? gve : BIGV;
                if (kk == 0) lmin0 = min(lmin0, v);
                else if (kk == 1) lmin1 = min(lmin1, v);
                else if (kk == 2) lmin2 = min(lmin2, v);
                else lmin3 = min(lmin3, v);
            }
        }
        sp[g] = packed;
    }

    // wave reduce, then cross-wave via LDS, then one partial record per block
    lmin0 = wred_min(lmin0); lmin1 = wred_min(lmin1);
    lmin2 = wred_min(lmin2); lmin3 = wred_min(lmin3);
    pres = wred_or(pres); gmax = wred_max(gmax);

    __shared__ int red[4][6];
    __shared__ int s_last;
    int wv = threadIdx.x >> 6, lane = threadIdx.x & 63;
    if (lane == 0) {
        red[wv][0] = lmin0; red[wv][1] = lmin1; red[wv][2] = lmin2;
        red[wv][3] = lmin3; red[wv][4] = pres;  red[wv][5] = gmax;
    }
    __syncthreads();
    if (threadIdx.x == 0) {
        int m0 = red[0][0], m1 = red[0][1], m2 = red[0][2], m3 = red[0][3];
        int pr = red[0][4], gm = red[0][5];
        for (int w2 = 1; w2 < 4; w2++) {
            m0 = min(m0, red[w2][0]); m1 = min(m1, red[w2][1]);
            m2 = min(m2, red[w2][2]); m3 = min(m3, red[w2][3]);
            pr |= red[w2][4]; gm = max(gm, red[w2][5]);
        }
        int* pp = wsi + ((size_t)plane * BPP + chunk) * PART_STRIDE;
        pp[0] = m0; pp[1] = m1; pp[2] = m2; pp[3] = m3; pp[4] = pr; pp[5] = gm;
        // release partials device-wide, then count this block done
        __threadfence();
        int done = atomicAdd(&wsi[CNT_IDX], 1);
        s_last = (done == NBLK - 1) ? 1 : 0;
    }
    __syncthreads();

    // ---- last-block tail: build the mapping (old kernel B, 4x wider reduce) ----
    if (s_last) {
        __threadfence();                 // acquire: see all other blocks' partials
        __shared__ int s_part[4][NPLANE][6];
        __shared__ int s_ov[NPLANE][4];
        __shared__ int s_pr[NPLANE];
        __shared__ int s_gm[NPLANE];

        int p = threadIdx.x & 63, q = threadIdx.x >> 6;   // 4 quarters x 64 planes
        {
            int m0 = INT_MAX, m1 = INT_MAX, m2 = INT_MAX, m3 = INT_MAX, pr = 0, gm = 0;
            int ch0 = q * 12, ch1 = min(BPP, ch0 + 12);
            for (int ch = ch0; ch < ch1; ch++) {
                const int* pp = wsi + ((size_t)p * BPP + ch) * PART_STRIDE;
                m0 = min(m0, pp[0]); m1 = min(m1, pp[1]);
                m2 = min(m2, pp[2]); m3 = min(m3, pp[3]);
                pr |= pp[4]; gm = max(gm, pp[5]);
            }
            s_part[q][p][0] = m0; s_part[q][p][1] = m1; s_part[q][p][2] = m2;
            s_part[q][p][3] = m3; s_part[q][p][4] = pr; s_part[q][p][5] = gm;
        }
        __syncthreads();
        if (threadIdx.x < NPLANE) {
            int pl = threadIdx.x;
            int m0 = INT_MAX, m1 = INT_MAX, m2 = INT_MAX, m3 = INT_MAX, pr = 0, gm = 0;
            for (int qq = 0; qq < 4; qq++) {
                m0 = min(m0, s_part[qq][pl][0]); m1 = min(m1, s_part[qq][pl][1]);
                m2 = min(m2, s_part[qq][pl][2]); m3 = min(m3, s_part[qq][pl][3]);
                pr |= s_part[qq][pl][4]; gm = max(gm, s_part[qq][pl][5]);
            }
            s_ov[pl][0] = m0; s_ov[pl][1] = m1; s_ov[pl][2] = m2; s_ov[pl][3] = m3;
            s_pr[pl] = pr; s_gm[pl] = gm;
        }
        __syncthreads();

        if (threadIdx.x < BB) {
            int bb = threadIdx.x;
            int max_id = 0;
            for (int ci = 0; ci < CC; ci++) max_id = max(max_id, s_gm[bb * CC + ci]);
            for (int ci = 0; ci < CC; ci++) {
                int pl = bb * CC + ci;
                int mbase = pl * KK;
                int id[KK], ov[KK], prb[KK];
                int prbits = s_pr[pl];
                for (int t = 0; t < KK; t++) {
                    id[t] = inst_ids[mbase + t];
                    ov[t] = s_ov[pl][t];
                    prb[t] = (prbits >> t) & 1;
                }
                int ord[KK] = {0, 1, 2, 3};
                for (int i = 1; i < KK; i++) {   // insertion sort by id
                    int key = ord[i], j = i - 1;
                    while (j >= 0 && id[ord[j]] > id[key]) { ord[j + 1] = ord[j]; j--; }
                    ord[j + 1] = key;
                }
                int map_slot[KK];
                int prev_id = -1, cur_map = 0, cnt_new = 0;
                for (int j = 0; j < KK; j++) {
                    int s = ord[j], l = id[s];
                    if (l != prev_id) {
                        int cov = INT_MAX, cpr = 0;
                        for (int t = 0; t < KK; t++)
                            if (id[t] == l) { cov = min(cov, ov[t]); cpr |= prb[t]; }
                        if (l == 0) cur_map = 0;
                        else {
                            bool has = cov < BIGV;
                            bool isnew = cpr && !has;
                            if (isnew) { cnt_new++; cur_map = max_id + cnt_new; }
                            else cur_map = has ? cov : 0;
                        }
                        prev_id = l;
                    }
                    map_slot[s] = cur_map;
                }
                for (int t = 0; t < KK; t++) wsi[MAP_OFF + mbase + t] = map_slot[t];
                max_id += cnt_new;
            }
        }
        // mapping visibility to the next kernel is guaranteed by the dispatch boundary
    }
}

// ============================================================================
// Kernel C: final remap from packed sel8:  p = s*50+g; out = s ? max(g, map[s-1]) : g
// ============================================================================
__global__ __launch_bounds__(TPB) void remap_kernel(
    const unsigned int* __restrict__ sel8, const int* __restrict__ wsi,
    int* __restrict__ out) {
    int plane = blockIdx.x / BPP;
    int chunk = blockIdx.x % BPP;

    int m0 = wsi[MAP_OFF + plane * 4 + 0];
    int m1 = wsi[MAP_OFF + plane * 4 + 1];
    int m2 = wsi[MAP_OFF + plane * 4 + 2];
    int m3 = wsi[MAP_OFF + plane * 4 + 3];

    const unsigned int* sp = sel8 + (size_t)plane * NG;
    v4i* op = (v4i*)(out + (size_t)plane * PLANE);

    int base = chunk * (TPB * GPT);
#pragma unroll
    for (int it = 0; it < GPT; it++) {
        int g = base + it * TPB + threadIdx.x;
        unsigned int u = sp[g];    // L2/L3-resident (written by pass A)
        v4i ov;
#pragma unroll
        for (int e = 0; e < 4; e++) {
            unsigned int p = (u >> (8 * e)) & 0xFFu;
            int s = (int)((p * 41u) >> 11);     // exact p/50 for p in [0,249]
            int gvv = (int)p - s * 50;
            int mv = (s == 1) ? m0 : (s == 2) ? m1 : (s == 3) ? m2 : m3;
            ov[e] = s ? max(gvv, mv) : gvv;
        }
        __builtin_nontemporal_store(ov, &op[g]);   // streaming output
    }
}

extern "C" void kernel_launch(void* const* d_in, const int* in_sizes, int n_in,
                              void* d_out, int out_size, void* d_ws, size_t ws_size,
                              hipStream_t stream) {
    const float* update = (const float*)d_in[0];
    const int* initmap = (const int*)d_in[1];
    const int* inst_ids = (const int*)d_in[2];
    int* out = (int*)d_out;

    unsigned int* sel8 = (unsigned int*)d_ws;
    int* wsi = (int*)((uint8_t*)d_ws + SEL8_BYTES);

    // zero the done-counter (workspace is poisoned between iterations)
    hipMemsetAsync(&wsi[CNT_IDX], 0, sizeof(int), stream);
    stats_map_kernel<<<NBLK, TPB, 0, stream>>>(update, initmap, inst_ids, sel8, wsi);
    remap_kernel<<<NBLK, TPB, 0, stream>>>(sel8, wsi, out);
}

// Round 5
// 413.139 us; speedup vs baseline: 1.4535x; 1.2704x over previous
//
#include <hip/hip_runtime.h>
#include <stdint.h>
#include <limits.h>

// Problem constants (fixed by the reference file)
#define BB 4
#define NI 64
#define CC 16
#define KK 4
#define HH 480
#define WW 480
#define PLANE (HH * WW)      // 230400 pixels per (b,c) plane
#define NG (PLANE / 4)       // 57600 groups-of-4-pixels per plane
#define BPP 45               // blocks per plane (45 * 256 * 5 = 57600 groups)
#define GPT 5
#define TPB 256
#define BIGV (1 << 30)
#define NPLANE (BB * CC)     // 64
#define NBLK (NPLANE * BPP)  // 2880 blocks

// Native vector types
typedef float  v4f __attribute__((ext_vector_type(4)));
typedef int    v4i __attribute__((ext_vector_type(4)));

// Workspace layout:
//   [0, SEL8_BYTES)  : uint8 per pixel, packed p = sel*50 + glob (one uint per 4 px)
//   ints after that:
//     partials[plane][chunk][8] : 64*45*8 ints (slots 0-3 overlap_min, 4 present, 5 gmax)
#define SEL8_BYTES ((size_t)NPLANE * PLANE)
#define PART_STRIDE 8

__device__ __forceinline__ int wred_min(int v) {
    for (int o = 32; o; o >>= 1) v = min(v, __shfl_down(v, o, 64));
    return v;
}
__device__ __forceinline__ int wred_max(int v) {
    for (int o = 32; o; o >>= 1) v = max(v, __shfl_down(v, o, 64));
    return v;
}
__device__ __forceinline__ int wred_or(int v) {
    for (int o = 32; o; o >>= 1) v |= __shfl_down(v, o, 64);
    return v;
}

// ============================================================================
// Kernel A: per-pixel (sel,glob) byte pack + per-block partial stats.
// EXACTLY the round-0 stats kernel (proven ~70 us). Round 4 showed that adding
// a threadfence+atomic last-block tail costs ~160 us (cross-XCD release fences
// + 2880 serialized same-line RMWs) — do NOT reintroduce it.
// ============================================================================
__global__ __launch_bounds__(TPB) void stats_kernel(
    const float* __restrict__ update, const int* __restrict__ initmap,
    const int* __restrict__ inst_ids, unsigned int* __restrict__ sel8,
    int* __restrict__ wsi) {
    int plane = blockIdx.x / BPP;       // 0..63  (b*16 + ci)
    int chunk = blockIdx.x % BPP;
    int b = plane >> 4;

    int idbase = plane * KK;
    int id0 = inst_ids[idbase + 0], id1 = inst_ids[idbase + 1];
    int id2 = inst_ids[idbase + 2], id3 = inst_ids[idbase + 3];

    const v4f* u0 = (const v4f*)(update + ((size_t)b * NI + id0) * PLANE);
    const v4f* u1 = (const v4f*)(update + ((size_t)b * NI + id1) * PLANE);
    const v4f* u2 = (const v4f*)(update + ((size_t)b * NI + id2) * PLANE);
    const v4f* u3 = (const v4f*)(update + ((size_t)b * NI + id3) * PLANE);
    const v4i* gl = (const v4i*)(initmap + (size_t)plane * PLANE);
    unsigned int* sp = sel8 + (size_t)plane * NG;

    int lmin0 = INT_MAX, lmin1 = INT_MAX, lmin2 = INT_MAX, lmin3 = INT_MAX;
    int pres = 0, gmax = 0;

    int base = chunk * (TPB * GPT);
#pragma unroll
    for (int it = 0; it < GPT; it++) {
        int g = base + it * TPB + threadIdx.x;
        // streaming inputs: nontemporal; sel8 store stays cached for pass C
        v4f a  = __builtin_nontemporal_load(&u0[g]);
        v4f b2 = __builtin_nontemporal_load(&u1[g]);
        v4f c  = __builtin_nontemporal_load(&u2[g]);
        v4f d  = __builtin_nontemporal_load(&u3[g]);
        v4i gv = __builtin_nontemporal_load(&gl[g]);

        unsigned int packed = 0;
#pragma unroll
        for (int e = 0; e < 4; e++) {
            float best = 1e-5f; int s = 0;
            if (a[e]  > best) { best = a[e];  s = 1; }
            if (b2[e] > best) { best = b2[e]; s = 2; }
            if (c[e]  > best) { best = c[e];  s = 3; }
            if (d[e]  > best) { s = 4; }
            int gve = gv[e];
            packed |= (unsigned int)(s * 50 + gve) << (8 * e);
            gmax = max(gmax, gve);
            if (s) {
                int kk = s - 1; pres |= 1 << kk;
                int v = gve ? gve : BIGV;
                if (kk == 0) lmin0 = min(lmin0, v);
                else if (kk == 1) lmin1 = min(lmin1, v);
                else if (kk == 2) lmin2 = min(lmin2, v);
                else lmin3 = min(lmin3, v);
            }
        }
        sp[g] = packed;
    }

    // wave reduce, then cross-wave via LDS, then one partial record per block
    lmin0 = wred_min(lmin0); lmin1 = wred_min(lmin1);
    lmin2 = wred_min(lmin2); lmin3 = wred_min(lmin3);
    pres = wred_or(pres); gmax = wred_max(gmax);

    __shared__ int red[4][6];
    int wv = threadIdx.x >> 6, lane = threadIdx.x & 63;
    if (lane == 0) {
        red[wv][0] = lmin0; red[wv][1] = lmin1; red[wv][2] = lmin2;
        red[wv][3] = lmin3; red[wv][4] = pres;  red[wv][5] = gmax;
    }
    __syncthreads();
    if (threadIdx.x == 0) {
        int m0 = red[0][0], m1 = red[0][1], m2 = red[0][2], m3 = red[0][3];
        int pr = red[0][4], gm = red[0][5];
        for (int w2 = 1; w2 < 4; w2++) {
            m0 = min(m0, red[w2][0]); m1 = min(m1, red[w2][1]);
            m2 = min(m2, red[w2][2]); m3 = min(m3, red[w2][3]);
            pr |= red[w2][4]; gm = max(gm, red[w2][5]);
        }
        int* pp = wsi + ((size_t)plane * BPP + chunk) * PART_STRIDE;
        pp[0] = m0; pp[1] = m1; pp[2] = m2; pp[3] = m3; pp[4] = pr; pp[5] = gm;
    }
}

// ============================================================================
// Kernel C': mapping construction (redundant per block — the twice-verified
// fused-kernel phase-2 logic) + final remap. Partials from A are visible via
// the dispatch boundary (no fences/atomics). The block's 5 sel8 words are
// prefetched into named registers BEFORE the mapping barrier, so the sel8
// read latency hides under the mapping computation.
// ============================================================================
__global__ __launch_bounds__(TPB) void remap_map_kernel(
    const unsigned int* __restrict__ sel8, const int* __restrict__ inst_ids,
    const int* __restrict__ wsi, int* __restrict__ out) {

    __shared__ int s_red[CC][6];
    __shared__ int s_ids[CC * KK];
    __shared__ int s_map[KK];

    int plane = blockIdx.x / BPP;
    int chunk = blockIdx.x % BPP;
    int b = plane >> 4;

    const unsigned int* sp = sel8 + (size_t)plane * NG;
    int base = chunk * (TPB * GPT);

    // prefetch this block's sel8 words (latency overlaps with mapping below)
    unsigned int u0 = sp[base + 0 * TPB + threadIdx.x];
    unsigned int u1 = sp[base + 1 * TPB + threadIdx.x];
    unsigned int u2 = sp[base + 2 * TPB + threadIdx.x];
    unsigned int u3 = sp[base + 3 * TPB + threadIdx.x];
    unsigned int u4 = sp[base + 4 * TPB + threadIdx.x];

    // ---- mapping prologue (per-block redundant; ~23 KB of L2-hot partials) ----
    if (threadIdx.x < CC * KK) s_ids[threadIdx.x] = inst_ids[b * (CC * KK) + threadIdx.x];
    if (threadIdx.x < CC * 6) {
        int p16 = threadIdx.x / 6, slot = threadIdx.x % 6;
        const int* rp = wsi + ((size_t)(b * CC + p16) * BPP) * PART_STRIDE + slot;
        int v = (slot < 4) ? INT_MAX : 0;
        for (int ch = 0; ch < BPP; ch++) {
            int x = rp[ch * PART_STRIDE];
            if (slot < 4)      v = min(v, x);
            else if (slot == 4) v |= x;
            else               v = max(v, x);
        }
        s_red[p16][slot] = v;
    }
    __syncthreads();

    if (threadIdx.x == 0) {
        int max_id = 0;
        for (int ci = 0; ci < CC; ci++) max_id = max(max_id, s_red[ci][5]);
        int my_ci = plane & (CC - 1);
        for (int ci = 0; ci <= my_ci; ci++) {
            int id[KK], ov[KK], prb[KK];
            int prbits = s_red[ci][4];
            for (int t = 0; t < KK; t++) {
                id[t] = s_ids[ci * KK + t];
                ov[t] = s_red[ci][t];
                prb[t] = (prbits >> t) & 1;
            }
            int ord[KK] = {0, 1, 2, 3};
            for (int i = 1; i < KK; i++) {       // insertion sort by id
                int key = ord[i], j = i - 1;
                while (j >= 0 && id[ord[j]] > id[key]) { ord[j + 1] = ord[j]; j--; }
                ord[j + 1] = key;
            }
            int map_slot[KK];
            int prev_id = -1, cur_map = 0, cnt_new = 0;
            for (int j = 0; j < KK; j++) {
                int s = ord[j], l = id[s];
                if (l != prev_id) {
                    int cov = INT_MAX, cpr = 0;
                    for (int t = 0; t < KK; t++)
                        if (id[t] == l) { cov = min(cov, ov[t]); cpr |= prb[t]; }
                    if (l == 0) cur_map = 0;
                    else {
                        bool has = cov < BIGV;
                        bool isnew = cpr && !has;
                        if (isnew) { cnt_new++; cur_map = max_id + cnt_new; }
                        else cur_map = has ? cov : 0;
                    }
                    prev_id = l;
                }
                map_slot[s] = cur_map;
            }
            if (ci == my_ci) {
                s_map[0] = map_slot[0]; s_map[1] = map_slot[1];
                s_map[2] = map_slot[2]; s_map[3] = map_slot[3];
            }
            max_id += cnt_new;
        }
    }
    __syncthreads();

    int m0 = s_map[0], m1 = s_map[1], m2 = s_map[2], m3 = s_map[3];

    // ---- remap the prefetched words, stream output ----
    v4i* op = (v4i*)(out + (size_t)plane * PLANE);
    unsigned int uu[GPT] = {u0, u1, u2, u3, u4};
#pragma unroll
    for (int it = 0; it < GPT; it++) {
        int g = base + it * TPB + threadIdx.x;
        unsigned int u = uu[it];
        v4i ov;
#pragma unroll
        for (int e = 0; e < 4; e++) {
            unsigned int p = (u >> (8 * e)) & 0xFFu;
            int s = (int)((p * 41u) >> 11);     // exact p/50 for p in [0,249]
            int gvv = (int)p - s * 50;
            int mv = (s == 1) ? m0 : (s == 2) ? m1 : (s == 3) ? m2 : m3;
            ov[e] = s ? max(gvv, mv) : gvv;
        }
        __builtin_nontemporal_store(ov, &op[g]);   // streaming output
    }
}

extern "C" void kernel_launch(void* const* d_in, const int* in_sizes, int n_in,
                              void* d_out, int out_size, void* d_ws, size_t ws_size,
                              hipStream_t stream) {
    const float* update = (const float*)d_in[0];
    const int* initmap = (const int*)d_in[1];
    const int* inst_ids = (const int*)d_in[2];
    int* out = (int*)d_out;

    unsigned int* sel8 = (unsigned int*)d_ws;
    int* wsi = (int*)((uint8_t*)d_ws + SEL8_BYTES);

    stats_kernel<<<NBLK, TPB, 0, stream>>>(update, initmap, inst_ids, sel8, wsi);
    remap_map_kernel<<<NBLK, TPB, 0, stream>>>(sel8, inst_ids, wsi, out);
}

// Round 7
// 397.524 us; speedup vs baseline: 1.5106x; 1.0393x over previous
//
#include <hip/hip_runtime.h>
#include <stdint.h>
#include <limits.h>

// Problem constants (fixed by the reference file)
#define BB 4
#define NI 64
#define CC 16
#define KK 4
#define HH 480
#define WW 480
#define PLANE (HH * WW)      // 230400 pixels per (b,c) plane
#define NG (PLANE / 4)       // 57600 groups-of-4-pixels per plane
#define BPP 45               // blocks per plane (45 * 256 * 5 = 57600 groups)
#define GPT 5
#define TPB 256
#define BIGV (1 << 30)
#define NPLANE (BB * CC)     // 64
#define NBLK (NPLANE * BPP)  // 2880

// Native vector types
typedef float  v4f __attribute__((ext_vector_type(4)));
typedef int    v4i __attribute__((ext_vector_type(4)));

// Workspace layout:
//   [0, SEL8_BYTES)  : packed p = sel*50 + glob per pixel (one uint per 4 px)
//   ints after that:
//     partials[plane][chunk][8] : 64*45*8 ints (0-3 overlap_min, 4 present, 5 gmax)
//     mapping[plane][4]         : 256 ints at MAP_OFF
#define SEL8_BYTES ((size_t)NPLANE * PLANE)
#define PART_STRIDE 8
#define MAP_OFF (NPLANE * BPP * PART_STRIDE)

// Session ledger (kernel-side time; total = this + ~293 us harness fill floor):
//   R0 A+B+C: 93us (best) | R1-3 fused coop: 344/192/302 | R4 atomic tail: +160
//   R5 redundant per-block map in C: +25 | R6: infra failure (no data), resubmit.
//   Conclusion: keep the 3-kernel shape; only B is parallelized (4 blocks,
//   verified fused-phase-2 gather).

__device__ __forceinline__ int wred_min(int v) {
    for (int o = 32; o; o >>= 1) v = min(v, __shfl_down(v, o, 64));
    return v;
}
__device__ __forceinline__ int wred_max(int v) {
    for (int o = 32; o; o >>= 1) v = max(v, __shfl_down(v, o, 64));
    return v;
}
__device__ __forceinline__ int wred_or(int v) {
    for (int o = 32; o; o >>= 1) v |= __shfl_down(v, o, 64);
    return v;
}

// ============================================================================
// Kernel A: per-pixel (sel,glob) byte pack + per-block partial stats.
// Byte-identical to the round-0 kernel (proven ~70 us, ~4.4 TB/s effective).
// ============================================================================
__global__ __launch_bounds__(TPB) void stats_kernel(
    const float* __restrict__ update, const int* __restrict__ initmap,
    const int* __restrict__ inst_ids, unsigned int* __restrict__ sel8,
    int* __restrict__ wsi) {
    int plane = blockIdx.x / BPP;       // 0..63  (b*16 + ci)
    int chunk = blockIdx.x % BPP;
    int b = plane >> 4;

    int idbase = plane * KK;
    int id0 = inst_ids[idbase + 0], id1 = inst_ids[idbase + 1];
    int id2 = inst_ids[idbase + 2], id3 = inst_ids[idbase + 3];

    const v4f* u0 = (const v4f*)(update + ((size_t)b * NI + id0) * PLANE);
    const v4f* u1 = (const v4f*)(update + ((size_t)b * NI + id1) * PLANE);
    const v4f* u2 = (const v4f*)(update + ((size_t)b * NI + id2) * PLANE);
    const v4f* u3 = (const v4f*)(update + ((size_t)b * NI + id3) * PLANE);
    const v4i* gl = (const v4i*)(initmap + (size_t)plane * PLANE);
    unsigned int* sp = sel8 + (size_t)plane * NG;

    int lmin0 = INT_MAX, lmin1 = INT_MAX, lmin2 = INT_MAX, lmin3 = INT_MAX;
    int pres = 0, gmax = 0;

    int base = chunk * (TPB * GPT);
#pragma unroll
    for (int it = 0; it < GPT; it++) {
        int g = base + it * TPB + threadIdx.x;
        // streaming inputs: nontemporal; sel8 store stays cached for pass C
        v4f a  = __builtin_nontemporal_load(&u0[g]);
        v4f b2 = __builtin_nontemporal_load(&u1[g]);
        v4f c  = __builtin_nontemporal_load(&u2[g]);
        v4f d  = __builtin_nontemporal_load(&u3[g]);
        v4i gv = __builtin_nontemporal_load(&gl[g]);

        unsigned int packed = 0;
#pragma unroll
        for (int e = 0; e < 4; e++) {
            float best = 1e-5f; int s = 0;
            if (a[e]  > best) { best = a[e];  s = 1; }
            if (b2[e] > best) { best = b2[e]; s = 2; }
            if (c[e]  > best) { best = c[e];  s = 3; }
            if (d[e]  > best) { s = 4; }
            int gve = gv[e];
            packed |= (unsigned int)(s * 50 + gve) << (8 * e);
            gmax = max(gmax, gve);
            if (s) {
                int kk = s - 1; pres |= 1 << kk;
                int v = gve ? gve : BIGV;
                if (kk == 0) lmin0 = min(lmin0, v);
                else if (kk == 1) lmin1 = min(lmin1, v);
                else if (kk == 2) lmin2 = min(lmin2, v);
                else lmin3 = min(lmin3, v);
            }
        }
        sp[g] = packed;
    }

    // wave reduce, then cross-wave via LDS, then one partial record per block
    lmin0 = wred_min(lmin0); lmin1 = wred_min(lmin1);
    lmin2 = wred_min(lmin2); lmin3 = wred_min(lmin3);
    pres = wred_or(pres); gmax = wred_max(gmax);

    __shared__ int red[4][6];
    int wv = threadIdx.x >> 6, lane = threadIdx.x & 63;
    if (lane == 0) {
        red[wv][0] = lmin0; red[wv][1] = lmin1; red[wv][2] = lmin2;
        red[wv][3] = lmin3; red[wv][4] = pres;  red[wv][5] = gmax;
    }
    __syncthreads();
    if (threadIdx.x == 0) {
        int m0 = red[0][0], m1 = red[0][1], m2 = red[0][2], m3 = red[0][3];
        int pr = red[0][4], gm = red[0][5];
        for (int w2 = 1; w2 < 4; w2++) {
            m0 = min(m0, red[w2][0]); m1 = min(m1, red[w2][1]);
            m2 = min(m2, red[w2][2]); m3 = min(m3, red[w2][3]);
            pr |= red[w2][4]; gm = max(gm, red[w2][5]);
        }
        int* pp = wsi + ((size_t)plane * BPP + chunk) * PART_STRIDE;
        pp[0] = m0; pp[1] = m1; pp[2] = m2; pp[3] = m3; pp[4] = pr; pp[5] = gm;
    }
}

// ============================================================================
// Kernel B': mapping construction, parallelized to 4 blocks (one per batch b).
// Gather phase = the thrice-verified fused-kernel phase-2 pattern (96 threads
// reduce 45 chunks x 16 planes x 6 slots in parallel); thread 0 then runs the
// tiny serial per-env mapping for all 16 ci and writes mapping[plane][4].
// ============================================================================
__global__ void mapping_kernel(const int* __restrict__ inst_ids, int* wsi) {
    __shared__ int s_red[CC][6];
    __shared__ int s_ids[CC * KK];

    int b = blockIdx.x;                  // 0..3

    if (threadIdx.x < CC * KK) s_ids[threadIdx.x] = inst_ids[b * (CC * KK) + threadIdx.x];
    if (threadIdx.x < CC * 6) {
        int p16 = threadIdx.x / 6, slot = threadIdx.x % 6;
        const int* rp = wsi + ((size_t)(b * CC + p16) * BPP) * PART_STRIDE + slot;
        int v = (slot < 4) ? INT_MAX : 0;
        for (int ch = 0; ch < BPP; ch++) {
            int x = rp[ch * PART_STRIDE];
            if (slot < 4)      v = min(v, x);
            else if (slot == 4) v |= x;
            else               v = max(v, x);
        }
        s_red[p16][slot] = v;
    }
    __syncthreads();

    if (threadIdx.x == 0) {
        int max_id = 0;
        for (int ci = 0; ci < CC; ci++) max_id = max(max_id, s_red[ci][5]);
        for (int ci = 0; ci < CC; ci++) {
            int pl = b * CC + ci;
            int mbase = pl * KK;
            int id[KK], ov[KK], prb[KK];
            int prbits = s_red[ci][4];
            for (int t = 0; t < KK; t++) {
                id[t] = s_ids[ci * KK + t];
                ov[t] = s_red[ci][t];
                prb[t] = (prbits >> t) & 1;
            }
            int ord[KK] = {0, 1, 2, 3};
            for (int i = 1; i < KK; i++) {       // insertion sort by id
                int key = ord[i], j = i - 1;
                while (j >= 0 && id[ord[j]] > id[key]) { ord[j + 1] = ord[j]; j--; }
                ord[j + 1] = key;
            }
            int map_slot[KK];
            int prev_id = -1, cur_map = 0, cnt_new = 0;
            for (int j = 0; j < KK; j++) {
                int s = ord[j], l = id[s];
                if (l != prev_id) {
                    int cov = INT_MAX, cpr = 0;
                    for (int t = 0; t < KK; t++)
                        if (id[t] == l) { cov = min(cov, ov[t]); cpr |= prb[t]; }
                    if (l == 0) cur_map = 0;
                    else {
                        bool has = cov < BIGV;
                        bool isnew = cpr && !has;
                        if (isnew) { cnt_new++; cur_map = max_id + cnt_new; }
                        else cur_map = has ? cov : 0;
                    }
                    prev_id = l;
                }
                map_slot[s] = cur_map;
            }
            for (int t = 0; t < KK; t++) wsi[MAP_OFF + mbase + t] = map_slot[t];
            max_id += cnt_new;
        }
    }
}

// ============================================================================
// Kernel C: final remap from packed sel8 (byte-identical to round 0):
//   p = s*50+g; out = s ? max(g, map[s-1]) : g
// ============================================================================
__global__ __launch_bounds__(TPB) void remap_kernel(
    const unsigned int* __restrict__ sel8, const int* __restrict__ wsi,
    int* __restrict__ out) {
    int plane = blockIdx.x / BPP;
    int chunk = blockIdx.x % BPP;

    int m0 = wsi[MAP_OFF + plane * 4 + 0];
    int m1 = wsi[MAP_OFF + plane * 4 + 1];
    int m2 = wsi[MAP_OFF + plane * 4 + 2];
    int m3 = wsi[MAP_OFF + plane * 4 + 3];

    const unsigned int* sp = sel8 + (size_t)plane * NG;
    v4i* op = (v4i*)(out + (size_t)plane * PLANE);

    int base = chunk * (TPB * GPT);
#pragma unroll
    for (int it = 0; it < GPT; it++) {
        int g = base + it * TPB + threadIdx.x;
        unsigned int u = sp[g];    // L2/L3-resident (written by pass A)
        v4i ov;
#pragma unroll
        for (int e = 0; e < 4; e++) {
            unsigned int p = (u >> (8 * e)) & 0xFFu;
            int s = (int)((p * 41u) >> 11);     // exact p/50 for p in [0,249]
            int gvv = (int)p - s * 50;
            int mv = (s == 1) ? m0 : (s == 2) ? m1 : (s == 3) ? m2 : m3;
            ov[e] = s ? max(gvv, mv) : gvv;
        }
        __builtin_nontemporal_store(ov, &op[g]);   // streaming output
    }
}

extern "C" void kernel_launch(void* const* d_in, const int* in_sizes, int n_in,
                              void* d_out, int out_size, void* d_ws, size_t ws_size,
                              hipStream_t stream) {
    const float* update = (const float*)d_in[0];
    const int* initmap = (const int*)d_in[1];
    const int* inst_ids = (const int*)d_in[2];
    int* out = (int*)d_out;

    unsigned int* sel8 = (unsigned int*)d_ws;
    int* wsi = (int*)((uint8_t*)d_ws + SEL8_BYTES);

    stats_kernel<<<NBLK, TPB, 0, stream>>>(update, initmap, inst_ids, sel8, wsi);
    mapping_kernel<<<BB, 128, 0, stream>>>(inst_ids, wsi);
    remap_kernel<<<NBLK, TPB, 0, stream>>>(sel8, wsi, out);
}

// Round 8
// 388.691 us; speedup vs baseline: 1.5449x; 1.0227x over previous
//
#include <hip/hip_runtime.h>
#include <stdint.h>
#include <limits.h>

// Problem constants (fixed by the reference file)
#define BB 4
#define NI 64
#define CC 16
#define KK 4
#define HH 480
#define WW 480
#define PLANE (HH * WW)      // 230400 pixels per (b,c) plane
#define NG (PLANE / 4)       // 57600 groups-of-4-pixels per plane
#define BPP 45               // blocks per plane (45 * 256 * 5 = 57600 groups)
#define GPT 5
#define TPB 256
#define BIGV (1 << 30)
#define NPLANE (BB * CC)     // 64
#define NBLK (NPLANE * BPP)  // 2880

// Native vector types
typedef float  v4f __attribute__((ext_vector_type(4)));
typedef int    v4i __attribute__((ext_vector_type(4)));

// Workspace layout:
//   [0, SEL8_BYTES)  : packed p = sel*50 + glob per pixel (one uint per 4 px)
//   ints after that:
//     partials[plane][chunk][8] : 64*45*8 ints (0-3 overlap_min, 4 present, 5 gmax)
//     mapping[plane][4]         : 256 ints at MAP_OFF
#define SEL8_BYTES ((size_t)NPLANE * PLANE)
#define PART_STRIDE 8
#define MAP_OFF (NPLANE * BPP * PART_STRIDE)

// Session ledger (kernel time = total - ~293us harness fill floor):
//   R0 A+B+C: ~93us best | R1-3 fused coop: 344/192/302 | R4 atomic tail: +160
//   R5 redundant map in C: +25 | R7 B' 4-block: +10 (reverted).
//   This round: ONLY A changes — depth-2 pipeline pinned by sched_barrier(0)
//   (hipcc provably sinks source-level prefetch otherwise: R0 VGPR=28, R3 spill).
//   Diagnosis keys: WRITE_SIZE(A)>>14.6MB => spilled => revert; total ~=388 =>
//   compiler already optimal => roofline.

__device__ __forceinline__ int wred_min(int v) {
    for (int o = 32; o; o >>= 1) v = min(v, __shfl_down(v, o, 64));
    return v;
}
__device__ __forceinline__ int wred_max(int v) {
    for (int o = 32; o; o >>= 1) v = max(v, __shfl_down(v, o, 64));
    return v;
}
__device__ __forceinline__ int wred_or(int v) {
    for (int o = 32; o; o >>= 1) v |= __shfl_down(v, o, 64);
    return v;
}

// ============================================================================
// Kernel A: per-pixel (sel,glob) byte pack + per-block partial stats.
// Depth-2 software pipeline: issue it+1's 5 loads, sched_barrier(0), consume it.
// The fence stops hipcc from sinking the load cluster (its JIT-load habit);
// the compiler still inserts its own counted vmcnt before the consumers.
// ~55-60 VGPR expected -> stays at 8 waves/SIMD.
// ============================================================================
__global__ __launch_bounds__(TPB) void stats_kernel(
    const float* __restrict__ update, const int* __restrict__ initmap,
    const int* __restrict__ inst_ids, unsigned int* __restrict__ sel8,
    int* __restrict__ wsi) {
    int plane = blockIdx.x / BPP;       // 0..63  (b*16 + ci)
    int chunk = blockIdx.x % BPP;
    int b = plane >> 4;

    int idbase = plane * KK;
    int id0 = inst_ids[idbase + 0], id1 = inst_ids[idbase + 1];
    int id2 = inst_ids[idbase + 2], id3 = inst_ids[idbase + 3];

    const v4f* u0 = (const v4f*)(update + ((size_t)b * NI + id0) * PLANE);
    const v4f* u1 = (const v4f*)(update + ((size_t)b * NI + id1) * PLANE);
    const v4f* u2 = (const v4f*)(update + ((size_t)b * NI + id2) * PLANE);
    const v4f* u3 = (const v4f*)(update + ((size_t)b * NI + id3) * PLANE);
    const v4i* gl = (const v4i*)(initmap + (size_t)plane * PLANE);
    unsigned int* sp = sel8 + (size_t)plane * NG;

    int lmin0 = INT_MAX, lmin1 = INT_MAX, lmin2 = INT_MAX, lmin3 = INT_MAX;
    int pres = 0, gmax = 0;

    int g = chunk * (TPB * GPT) + threadIdx.x;

    // prologue: it=0 loads
    v4f a  = __builtin_nontemporal_load(&u0[g]);
    v4f b2 = __builtin_nontemporal_load(&u1[g]);
    v4f c  = __builtin_nontemporal_load(&u2[g]);
    v4f d  = __builtin_nontemporal_load(&u3[g]);
    v4i gv = __builtin_nontemporal_load(&gl[g]);

#pragma unroll
    for (int it = 0; it < GPT; it++) {
        v4f na, nb, nc, nd; v4i ngv;
        int gn = g + TPB;
        if (it + 1 < GPT) {                  // folds at compile time (full unroll)
            na  = __builtin_nontemporal_load(&u0[gn]);
            nb  = __builtin_nontemporal_load(&u1[gn]);
            nc  = __builtin_nontemporal_load(&u2[gn]);
            nd  = __builtin_nontemporal_load(&u3[gn]);
            ngv = __builtin_nontemporal_load(&gl[gn]);
        }
        // pin: loads above may not sink below; consumers below may not hoist above
        __builtin_amdgcn_sched_barrier(0);

        unsigned int packed = 0;
#pragma unroll
        for (int e = 0; e < 4; e++) {
            float best = 1e-5f; int s = 0;
            if (a[e]  > best) { best = a[e];  s = 1; }
            if (b2[e] > best) { best = b2[e]; s = 2; }
            if (c[e]  > best) { best = c[e];  s = 3; }
            if (d[e]  > best) { s = 4; }
            int gve = gv[e];
            packed |= (unsigned int)(s * 50 + gve) << (8 * e);
            gmax = max(gmax, gve);
            if (s) {
                int kk = s - 1; pres |= 1 << kk;
                int v = gve ? gve : BIGV;
                if (kk == 0) lmin0 = min(lmin0, v);
                else if (kk == 1) lmin1 = min(lmin1, v);
                else if (kk == 2) lmin2 = min(lmin2, v);
                else lmin3 = min(lmin3, v);
            }
        }
        sp[g] = packed;                      // sel8 stays cached for pass C

        if (it + 1 < GPT) {                  // rotate pipeline registers
            a = na; b2 = nb; c = nc; d = nd; gv = ngv;
        }
        g = gn;
    }

    // wave reduce, then cross-wave via LDS, then one partial record per block
    lmin0 = wred_min(lmin0); lmin1 = wred_min(lmin1);
    lmin2 = wred_min(lmin2); lmin3 = wred_min(lmin3);
    pres = wred_or(pres); gmax = wred_max(gmax);

    __shared__ int red[4][6];
    int wv = threadIdx.x >> 6, lane = threadIdx.x & 63;
    if (lane == 0) {
        red[wv][0] = lmin0; red[wv][1] = lmin1; red[wv][2] = lmin2;
        red[wv][3] = lmin3; red[wv][4] = pres;  red[wv][5] = gmax;
    }
    __syncthreads();
    if (threadIdx.x == 0) {
        int m0 = red[0][0], m1 = red[0][1], m2 = red[0][2], m3 = red[0][3];
        int pr = red[0][4], gm = red[0][5];
        for (int w2 = 1; w2 < 4; w2++) {
            m0 = min(m0, red[w2][0]); m1 = min(m1, red[w2][1]);
            m2 = min(m2, red[w2][2]); m3 = min(m3, red[w2][3]);
            pr |= red[w2][4]; gm = max(gm, red[w2][5]);
        }
        int* pp = wsi + ((size_t)plane * BPP + chunk) * PART_STRIDE;
        pp[0] = m0; pp[1] = m1; pp[2] = m2; pp[3] = m3; pp[4] = pr; pp[5] = gm;
    }
}

// ============================================================================
// Kernel B: reduce partials + sequential per-env mapping construction.
// Byte-identical to the round-0 original (R7 showed the 4-block variant is
// neutral-to-negative; keep the proven one).
// ============================================================================
__global__ void mapping_kernel(const int* __restrict__ inst_ids, int* wsi) {
    __shared__ int s_ov[NPLANE][4];
    __shared__ int s_pr[NPLANE];
    __shared__ int s_gm[NPLANE];

    int plane = threadIdx.x;  // 64 threads, one per plane
    int m0 = INT_MAX, m1 = INT_MAX, m2 = INT_MAX, m3 = INT_MAX, pr = 0, gm = 0;
    for (int ch = 0; ch < BPP; ch++) {
        const int* pp = wsi + ((size_t)plane * BPP + ch) * PART_STRIDE;
        m0 = min(m0, pp[0]); m1 = min(m1, pp[1]);
        m2 = min(m2, pp[2]); m3 = min(m3, pp[3]);
        pr |= pp[4]; gm = max(gm, pp[5]);
    }
    s_ov[plane][0] = m0; s_ov[plane][1] = m1;
    s_ov[plane][2] = m2; s_ov[plane][3] = m3;
    s_pr[plane] = pr; s_gm[plane] = gm;
    __syncthreads();

    if (threadIdx.x < BB) {
        int b = threadIdx.x;
        int max_id = 0;
        for (int ci = 0; ci < CC; ci++) max_id = max(max_id, s_gm[b * CC + ci]);
        for (int ci = 0; ci < CC; ci++) {
            int pl = b * CC + ci;
            int base = pl * KK;
            int id[KK], ov[KK], prb[KK];
            int prbits = s_pr[pl];
            for (int t = 0; t < KK; t++) {
                id[t] = inst_ids[base + t];
                ov[t] = s_ov[pl][t];
                prb[t] = (prbits >> t) & 1;
            }
            int ord[KK] = {0, 1, 2, 3};
            for (int i = 1; i < KK; i++) {       // insertion sort by id
                int key = ord[i], j = i - 1;
                while (j >= 0 && id[ord[j]] > id[key]) { ord[j + 1] = ord[j]; j--; }
                ord[j + 1] = key;
            }
            int map_slot[KK];
            int prev_id = -1, cur_map = 0, cnt_new = 0;
            for (int j = 0; j < KK; j++) {
                int s = ord[j], l = id[s];
                if (l != prev_id) {
                    int cov = INT_MAX, cpr = 0;
                    for (int t = 0; t < KK; t++)
                        if (id[t] == l) { cov = min(cov, ov[t]); cpr |= prb[t]; }
                    if (l == 0) cur_map = 0;
                    else {
                        bool has = cov < BIGV;
                        bool isnew = cpr && !has;
                        if (isnew) { cnt_new++; cur_map = max_id + cnt_new; }
                        else cur_map = has ? cov : 0;
                    }
                    prev_id = l;
                }
                map_slot[s] = cur_map;
            }
            for (int t = 0; t < KK; t++) wsi[MAP_OFF + base + t] = map_slot[t];
            max_id += cnt_new;
        }
    }
}

// ============================================================================
// Kernel C: final remap from packed sel8 (byte-identical to round 0):
//   p = s*50+g; out = s ? max(g, map[s-1]) : g
// ============================================================================
__global__ __launch_bounds__(TPB) void remap_kernel(
    const unsigned int* __restrict__ sel8, const int* __restrict__ wsi,
    int* __restrict__ out) {
    int plane = blockIdx.x / BPP;
    int chunk = blockIdx.x % BPP;

    int m0 = wsi[MAP_OFF + plane * 4 + 0];
    int m1 = wsi[MAP_OFF + plane * 4 + 1];
    int m2 = wsi[MAP_OFF + plane * 4 + 2];
    int m3 = wsi[MAP_OFF + plane * 4 + 3];

    const unsigned int* sp = sel8 + (size_t)plane * NG;
    v4i* op = (v4i*)(out + (size_t)plane * PLANE);

    int base = chunk * (TPB * GPT);
#pragma unroll
    for (int it = 0; it < GPT; it++) {
        int g = base + it * TPB + threadIdx.x;
        unsigned int u = sp[g];    // L2/L3-resident (written by pass A)
        v4i ov;
#pragma unroll
        for (int e = 0; e < 4; e++) {
            unsigned int p = (u >> (8 * e)) & 0xFFu;
            int s = (int)((p * 41u) >> 11);     // exact p/50 for p in [0,249]
            int gvv = (int)p - s * 50;
            int mv = (s == 1) ? m0 : (s == 2) ? m1 : (s == 3) ? m2 : m3;
            ov[e] = s ? max(gvv, mv) : gvv;
        }
        __builtin_nontemporal_store(ov, &op[g]);   // streaming output
    }
}

extern "C" void kernel_launch(void* const* d_in, const int* in_sizes, int n_in,
                              void* d_out, int out_size, void* d_ws, size_t ws_size,
                              hipStream_t stream) {
    const float* update = (const float*)d_in[0];
    const int* initmap = (const int*)d_in[1];
    const int* inst_ids = (const int*)d_in[2];
    int* out = (int*)d_out;

    unsigned int* sel8 = (unsigned int*)d_ws;
    int* wsi = (int*)((uint8_t*)d_ws + SEL8_BYTES);

    stats_kernel<<<NBLK, TPB, 0, stream>>>(update, initmap, inst_ids, sel8, wsi);
    mapping_kernel<<<1, NPLANE, 0, stream>>>(inst_ids, wsi);
    remap_kernel<<<NBLK, TPB, 0, stream>>>(sel8, wsi, out);
}